// Round 1
// baseline (738.129 us; speedup 1.0000x reference)
//
#include <hip/hip_runtime.h>
#include <math.h>

#define FEAT   2048
#define RED    512
#define NROI   4
#define FLATSZ 25088   // 512*49
#define H1SZ   4096
#define H2SZ   2048
#define NCLS   21
#define NREG   80

__device__ __forceinline__ float wave_reduce_sum(float v) {
#pragma unroll
    for (int off = 32; off >= 1; off >>= 1)
        v += __shfl_xor(v, off, 64);
    return v;
}

// ---------------------------------------------------------------------------
// Kernel 1: ROI adaptive avg pool.
// grid = NROI * FEAT * 7 blocks of 64 threads (1 wave).
// Block handles one (roi, channel, hb) strip: rows [hs,he), all columns.
// Lane j owns columns j and j+64; each column feeds <=2 output w-bins.
// crop = base_x[0, :, x:x+w, y:y+h]  =>  Hc = w (rows), Wc = h (cols).
// ---------------------------------------------------------------------------
__global__ __launch_bounds__(64) void pool_kernel(const float* __restrict__ base_x,
                                                  const int* __restrict__ rois,
                                                  float* __restrict__ pooled) {
    int bx   = blockIdx.x;
    int hb   = bx % 7;
    int c    = (bx / 7) % FEAT;
    int r    = bx / (7 * FEAT);
    int lane = threadIdx.x;

    const int* roi = rois + r * 4;
    int x = roi[0], y = roi[1];
    int Wc = roi[2];           // h -> column extent
    int Hc = roi[3];           // w -> row extent

    int hs = (hb * Hc) / 7;
    int he = ((hb + 1) * Hc + 6) / 7;

    int j0 = lane, j1 = lane + 64;
    int b00 = -1, b01 = -1, b10 = -1, b11 = -1;
#pragma unroll
    for (int b = 0; b < 7; ++b) {
        int wsb = (b * Wc) / 7;
        int web = ((b + 1) * Wc + 6) / 7;
        if (j0 >= wsb && j0 < web) { if (b00 < 0) b00 = b; else b01 = b; }
        if (j1 >= wsb && j1 < web) { if (b10 < 0) b10 = b; else b11 = b; }
    }

    const float* plane = base_x + (size_t)c * 16384 + y;
    float s0 = 0.f, s1 = 0.f;
    for (int i = hs; i < he; ++i) {
        const float* rowp = plane + (size_t)(x + i) * 128;
        if (j0 < Wc) s0 += rowp[j0];
        if (j1 < Wc) s1 += rowp[j1];
    }

    float hspan = (float)(he - hs);
#pragma unroll
    for (int b = 0; b < 7; ++b) {
        float v = (((b == b00) || (b == b01)) ? s0 : 0.f) +
                  (((b == b10) || (b == b11)) ? s1 : 0.f);
        v = wave_reduce_sum(v);
        if (lane == 0) {
            int wsb = (b * Wc) / 7;
            int web = ((b + 1) * Wc + 6) / 7;
            float area = hspan * (float)(web - wsb);
            pooled[((size_t)r * FEAT + c) * 49 + hb * 7 + b] = v / area;
        }
    }
}

// ---------------------------------------------------------------------------
// Kernel 2: 1x1 conv 2048 -> 512 over (4 rois x 49 px), writes flat[4][25088].
// grid = NROI * (RED/4) blocks of 256 threads.
// Block = (roi r, 4 output channels o0..o0+3). Wave w reduces K-slice
// [w*512,(w+1)*512); lanes = 49 spatial positions (coalesced loads).
// ---------------------------------------------------------------------------
__global__ __launch_bounds__(256) void conv_kernel(const float* __restrict__ pooled,
                                                   const float* __restrict__ conv_w,
                                                   const float* __restrict__ conv_b,
                                                   float* __restrict__ flat) {
    int bx = blockIdx.x;
    int r  = bx >> 7;              // / 128
    int o0 = (bx & 127) * 4;
    int tid  = threadIdx.x;
    int wave = tid >> 6, lane = tid & 63;
    int hw = lane < 49 ? lane : 48;   // clamp: lanes 49..63 compute garbage, unused

    const float* pp  = pooled + (size_t)r * FEAT * 49 + hw;
    const float* w0p = conv_w + (size_t)(o0 + 0) * FEAT;
    const float* w1p = conv_w + (size_t)(o0 + 1) * FEAT;
    const float* w2p = conv_w + (size_t)(o0 + 2) * FEAT;
    const float* w3p = conv_w + (size_t)(o0 + 3) * FEAT;

    float a0 = 0.f, a1 = 0.f, a2 = 0.f, a3 = 0.f;
    int c0 = wave * 512;
#pragma unroll 8
    for (int c = c0; c < c0 + 512; ++c) {
        float v = pp[(size_t)c * 49];
        a0 += w0p[c] * v;
        a1 += w1p[c] * v;
        a2 += w2p[c] * v;
        a3 += w3p[c] * v;
    }

    __shared__ float lds[4][4][64];
    lds[wave][0][lane] = a0;
    lds[wave][1][lane] = a1;
    lds[wave][2][lane] = a2;
    lds[wave][3][lane] = a3;
    __syncthreads();

    if (lane < 49) {
        int od = wave;   // wave w finalizes output channel o0+w
        float v = lds[0][od][lane] + lds[1][od][lane] + lds[2][od][lane] + lds[3][od][lane];
        flat[(size_t)r * FLATSZ + (size_t)(o0 + od) * 49 + lane] = v + conv_b[o0 + od];
    }
}

// ---------------------------------------------------------------------------
// Kernels 3/4: dense layer as row-parallel GEMV over 4 rois.
// grid = N/4 blocks of 256 threads; block computes 4 weight rows x 4 rois.
// K4 = K/4 float4 elements per row.
// ---------------------------------------------------------------------------
#define DOT4(a, b) ((a).x * (b).x + (a).y * (b).y + (a).z * (b).z + (a).w * (b).w)

template <int K4, int ACT_LD, int OUT_LD, bool RELU>
__global__ __launch_bounds__(256) void gemv_rows4(const float* __restrict__ act,
                                                  const float* __restrict__ w,
                                                  const float* __restrict__ bias,
                                                  float* __restrict__ out) {
    const int j0  = blockIdx.x * 4;
    const int tid = threadIdx.x;
    const int K   = K4 * 4;

    const float4* w0 = (const float4*)(w + (size_t)(j0 + 0) * K);
    const float4* w1 = (const float4*)(w + (size_t)(j0 + 1) * K);
    const float4* w2 = (const float4*)(w + (size_t)(j0 + 2) * K);
    const float4* w3 = (const float4*)(w + (size_t)(j0 + 3) * K);
    const float4* a0 = (const float4*)(act + 0 * (size_t)ACT_LD);
    const float4* a1 = (const float4*)(act + 1 * (size_t)ACT_LD);
    const float4* a2 = (const float4*)(act + 2 * (size_t)ACT_LD);
    const float4* a3 = (const float4*)(act + 3 * (size_t)ACT_LD);

    float acc[16];
#pragma unroll
    for (int i = 0; i < 16; ++i) acc[i] = 0.f;

    for (int k = tid; k < K4; k += 256) {
        float4 va0 = a0[k], va1 = a1[k], va2 = a2[k], va3 = a3[k];
        float4 vw0 = w0[k], vw1 = w1[k], vw2 = w2[k], vw3 = w3[k];
        acc[0]  += DOT4(vw0, va0); acc[1]  += DOT4(vw0, va1); acc[2]  += DOT4(vw0, va2); acc[3]  += DOT4(vw0, va3);
        acc[4]  += DOT4(vw1, va0); acc[5]  += DOT4(vw1, va1); acc[6]  += DOT4(vw1, va2); acc[7]  += DOT4(vw1, va3);
        acc[8]  += DOT4(vw2, va0); acc[9]  += DOT4(vw2, va1); acc[10] += DOT4(vw2, va2); acc[11] += DOT4(vw2, va3);
        acc[12] += DOT4(vw3, va0); acc[13] += DOT4(vw3, va1); acc[14] += DOT4(vw3, va2); acc[15] += DOT4(vw3, va3);
    }

#pragma unroll
    for (int i = 0; i < 16; ++i) acc[i] = wave_reduce_sum(acc[i]);

    __shared__ float lds[4][16];
    int wave = tid >> 6, lane = tid & 63;
    if (lane == 0) {
#pragma unroll
        for (int i = 0; i < 16; ++i) lds[wave][i] = acc[i];
    }
    __syncthreads();

    if (tid < 16) {
        float v  = lds[0][tid] + lds[1][tid] + lds[2][tid] + lds[3][tid];
        int   jj = tid >> 2, rr = tid & 3;
        int   j  = j0 + jj;
        v += bias[j];
        if (RELU) v = fmaxf(v, 0.f);
        out[(size_t)rr * OUT_LD + j] = v;
    }
}

// ---------------------------------------------------------------------------
// Kernel 5: class logits (21 rows -> ws) + regr (80 rows -> d_out[84..]).
// grid = 101 blocks. K = 2048.
// ---------------------------------------------------------------------------
__global__ __launch_bounds__(256) void head_kernel(const float* __restrict__ h2,
                                                   const float* __restrict__ d3_w,
                                                   const float* __restrict__ d4_w,
                                                   float* __restrict__ logits,
                                                   float* __restrict__ out) {
    int i = blockIdx.x;   // 0..100
    const float* wrow = (i < NCLS) ? (d3_w + (size_t)i * H2SZ)
                                   : (d4_w + (size_t)(i - NCLS) * H2SZ);
    int tid = threadIdx.x;
    const float4* w4 = (const float4*)wrow;
    const float4* a0 = (const float4*)(h2);
    const float4* a1 = (const float4*)(h2 + H2SZ);
    const float4* a2 = (const float4*)(h2 + 2 * H2SZ);
    const float4* a3 = (const float4*)(h2 + 3 * H2SZ);

    float acc0 = 0.f, acc1 = 0.f, acc2 = 0.f, acc3 = 0.f;
    for (int k = tid; k < 512; k += 256) {
        float4 w = w4[k];
        acc0 += DOT4(w, a0[k]);
        acc1 += DOT4(w, a1[k]);
        acc2 += DOT4(w, a2[k]);
        acc3 += DOT4(w, a3[k]);
    }
    acc0 = wave_reduce_sum(acc0);
    acc1 = wave_reduce_sum(acc1);
    acc2 = wave_reduce_sum(acc2);
    acc3 = wave_reduce_sum(acc3);

    __shared__ float lds[4][4];
    int wave = tid >> 6, lane = tid & 63;
    if (lane == 0) { lds[wave][0] = acc0; lds[wave][1] = acc1; lds[wave][2] = acc2; lds[wave][3] = acc3; }
    __syncthreads();

    if (tid < 4) {
        float v = lds[0][tid] + lds[1][tid] + lds[2][tid] + lds[3][tid];
        if (i < NCLS) logits[tid * NCLS + i] = v;
        else          out[NROI * NCLS + tid * NREG + (i - NCLS)] = v;
    }
}

// ---------------------------------------------------------------------------
// Kernel 6: softmax over 21 classes per roi. 1 block, wave = roi.
// ---------------------------------------------------------------------------
__global__ __launch_bounds__(256) void softmax_kernel(const float* __restrict__ logits,
                                                      float* __restrict__ out) {
    int tid = threadIdx.x;
    int r = tid >> 6, lane = tid & 63;
    float v = (lane < NCLS) ? logits[r * NCLS + lane] : -INFINITY;
    float m = v;
#pragma unroll
    for (int off = 32; off >= 1; off >>= 1)
        m = fmaxf(m, __shfl_xor(m, off, 64));
    float e = (lane < NCLS) ? expf(v - m) : 0.f;
    float s = wave_reduce_sum(e);
    if (lane < NCLS) out[r * NCLS + lane] = e / s;
}

// ---------------------------------------------------------------------------
extern "C" void kernel_launch(void* const* d_in, const int* in_sizes, int n_in,
                              void* d_out, int out_size, void* d_ws, size_t ws_size,
                              hipStream_t stream) {
    (void)in_sizes; (void)n_in; (void)out_size; (void)ws_size;
    const float* base_x = (const float*)d_in[0];
    const int*   rois   = (const int*)d_in[1];
    const float* conv_w = (const float*)d_in[2];
    const float* conv_b = (const float*)d_in[3];
    const float* d1_w   = (const float*)d_in[4];
    const float* d1_b   = (const float*)d_in[5];
    const float* d2_w   = (const float*)d_in[6];
    const float* d2_b   = (const float*)d_in[7];
    const float* d3_w   = (const float*)d_in[8];
    const float* d4_w   = (const float*)d_in[9];
    float* out = (float*)d_out;

    // workspace carve (all offsets 16B-aligned); total ~2.1 MB
    char*  ws     = (char*)d_ws;
    float* pooled = (float*)(ws);                 // 4*2048*49   = 1,605,632 B
    float* flat   = (float*)(ws + 1605632);       // 4*25088    =   401,408 B
    float* h1     = (float*)(ws + 2007040);       // 4*4096     =    65,536 B
    float* h2     = (float*)(ws + 2072576);       // 4*2048     =    32,768 B
    float* logits = (float*)(ws + 2105344);       // 4*21       =       336 B

    pool_kernel<<<NROI * FEAT * 7, 64, 0, stream>>>(base_x, rois, pooled);
    conv_kernel<<<NROI * (RED / 4), 256, 0, stream>>>(pooled, conv_w, conv_b, flat);
    gemv_rows4<FLATSZ / 4, FLATSZ, H1SZ, true><<<H1SZ / 4, 256, 0, stream>>>(flat, d1_w, d1_b, h1);
    gemv_rows4<H1SZ / 4, H1SZ, H2SZ, true><<<H2SZ / 4, 256, 0, stream>>>(h1, d2_w, d2_b, h2);
    head_kernel<<<NCLS + NREG, 256, 0, stream>>>(h2, d3_w, d4_w, logits, out);
    softmax_kernel<<<1, 256, 0, stream>>>(logits, out);
}

// Round 2
// 701.121 us; speedup vs baseline: 1.0528x; 1.0528x over previous
//
#include <hip/hip_runtime.h>
#include <math.h>

#define FEAT   2048
#define RED    512
#define NROI   4
#define FLATSZ 25088   // 512*49
#define H1SZ   4096
#define H2SZ   2048
#define NCLS   21
#define NREG   80

__device__ __forceinline__ float wave_reduce_sum(float v) {
#pragma unroll
    for (int off = 32; off >= 1; off >>= 1)
        v += __shfl_xor(v, off, 64);
    return v;
}

// ---------------------------------------------------------------------------
// Kernel 1 (v2): ROI adaptive avg pool.
// grid = NROI * FEAT/4 blocks of 256 threads; wave w handles channel cg*4+w.
// One wave does all 7 h-strips of its (roi, channel): per strip, lanes hold
// column partial sums (cols j and j+64), written to LDS; final phase lanes
// 0..48 each sum their (hb,wb) column range. No wave shuffles.
// crop = base_x[0, :, x:x+w, y:y+h]  =>  Hc = w (rows), Wc = h (cols).
// ---------------------------------------------------------------------------
__global__ __launch_bounds__(256) void pool_kernel(const float* __restrict__ base_x,
                                                   const int* __restrict__ rois,
                                                   float* __restrict__ pooled) {
    int bx   = blockIdx.x;
    int r    = bx >> 9;          // / (FEAT/4)
    int cg   = bx & 511;
    int tid  = threadIdx.x;
    int wave = tid >> 6, lane = tid & 63;
    int c    = cg * 4 + wave;

    const int* roi = rois + r * 4;
    int x = roi[0], y = roi[1];
    int Wc = roi[2];             // h -> column extent
    int Hc = roi[3];             // w -> row extent

    __shared__ float cs[4][7][130];   // [wave][hb][col], pad to 130 for banks

    const float* plane = base_x + (size_t)c * 16384 + y;
    int j0 = lane, j1 = lane + 64;
    bool p0 = (j0 < Wc), p1 = (j1 < Wc);

#pragma unroll
    for (int b = 0; b < 7; ++b) {
        int hs = (b * Hc) / 7;
        int he = ((b + 1) * Hc + 6) / 7;
        float s0 = 0.f, s1 = 0.f;
        int i = hs;
        for (; i + 2 <= he; i += 2) {
            const float* r0 = plane + (size_t)(x + i) * 128;
            float t0 = p0 ? r0[j0] : 0.f;
            float t1 = p1 ? r0[j1] : 0.f;
            float t2 = p0 ? r0[128 + j0] : 0.f;
            float t3 = p1 ? r0[128 + j1] : 0.f;
            s0 += t0 + t2;
            s1 += t1 + t3;
        }
        if (i < he) {
            const float* r0 = plane + (size_t)(x + i) * 128;
            if (p0) s0 += r0[j0];
            if (p1) s1 += r0[j1];
        }
        cs[wave][b][j0] = s0;
        cs[wave][b][j1] = s1;
    }
    __syncthreads();   // all 4 waves have identical trip counts (same roi)

    if (lane < 49) {
        int hb = lane / 7, wb = lane % 7;
        int hs = (hb * Hc) / 7, he = ((hb + 1) * Hc + 6) / 7;
        int ws = (wb * Wc) / 7, we = ((wb + 1) * Wc + 6) / 7;
        float s = 0.f;
        for (int k = ws; k < we; ++k) s += cs[wave][hb][k];
        float area = (float)(he - hs) * (float)(we - ws);
        pooled[((size_t)r * FEAT + c) * 49 + lane] = s / area;
    }
}

// ---------------------------------------------------------------------------
// Kernel 2: 1x1 conv 2048 -> 512 over (4 rois x 49 px), writes flat[4][25088].
// grid = NROI * (RED/4) blocks of 256 threads.
// Block = (roi r, 4 output channels o0..o0+3). Wave w reduces K-slice
// [w*512,(w+1)*512); lanes = 49 spatial positions (coalesced loads).
// ---------------------------------------------------------------------------
__global__ __launch_bounds__(256) void conv_kernel(const float* __restrict__ pooled,
                                                   const float* __restrict__ conv_w,
                                                   const float* __restrict__ conv_b,
                                                   float* __restrict__ flat) {
    int bx = blockIdx.x;
    int r  = bx >> 7;              // / 128
    int o0 = (bx & 127) * 4;
    int tid  = threadIdx.x;
    int wave = tid >> 6, lane = tid & 63;
    int hw = lane < 49 ? lane : 48;   // clamp: lanes 49..63 compute garbage, unused

    const float* pp  = pooled + (size_t)r * FEAT * 49 + hw;
    const float* w0p = conv_w + (size_t)(o0 + 0) * FEAT;
    const float* w1p = conv_w + (size_t)(o0 + 1) * FEAT;
    const float* w2p = conv_w + (size_t)(o0 + 2) * FEAT;
    const float* w3p = conv_w + (size_t)(o0 + 3) * FEAT;

    float a0 = 0.f, a1 = 0.f, a2 = 0.f, a3 = 0.f;
    int c0 = wave * 512;
#pragma unroll 8
    for (int c = c0; c < c0 + 512; ++c) {
        float v = pp[(size_t)c * 49];
        a0 += w0p[c] * v;
        a1 += w1p[c] * v;
        a2 += w2p[c] * v;
        a3 += w3p[c] * v;
    }

    __shared__ float lds[4][4][64];
    lds[wave][0][lane] = a0;
    lds[wave][1][lane] = a1;
    lds[wave][2][lane] = a2;
    lds[wave][3][lane] = a3;
    __syncthreads();

    if (lane < 49) {
        int od = wave;   // wave w finalizes output channel o0+w
        float v = lds[0][od][lane] + lds[1][od][lane] + lds[2][od][lane] + lds[3][od][lane];
        flat[(size_t)r * FLATSZ + (size_t)(o0 + od) * 49 + lane] = v + conv_b[o0 + od];
    }
}

// ---------------------------------------------------------------------------
// Kernels 3/4: dense layer as row-parallel GEMV over 4 rois.
// grid = N/4 blocks of 256 threads; block computes 4 weight rows x 4 rois.
// K4 = K/4 float4 elements per row. Weights issued first (HBM stream),
// activations second (L2/L3 hits); unroll 2 -> 16 loads in flight.
// ---------------------------------------------------------------------------
#define DOT4(a, b) ((a).x * (b).x + (a).y * (b).y + (a).z * (b).z + (a).w * (b).w)

template <int K4, int ACT_LD, int OUT_LD, bool RELU>
__global__ __launch_bounds__(256) void gemv_rows4(const float* __restrict__ act,
                                                  const float* __restrict__ w,
                                                  const float* __restrict__ bias,
                                                  float* __restrict__ out) {
    const int j0  = blockIdx.x * 4;
    const int tid = threadIdx.x;
    const int K   = K4 * 4;

    const float4* w0 = (const float4*)(w + (size_t)(j0 + 0) * K);
    const float4* w1 = (const float4*)(w + (size_t)(j0 + 1) * K);
    const float4* w2 = (const float4*)(w + (size_t)(j0 + 2) * K);
    const float4* w3 = (const float4*)(w + (size_t)(j0 + 3) * K);
    const float4* a0 = (const float4*)(act + 0 * (size_t)ACT_LD);
    const float4* a1 = (const float4*)(act + 1 * (size_t)ACT_LD);
    const float4* a2 = (const float4*)(act + 2 * (size_t)ACT_LD);
    const float4* a3 = (const float4*)(act + 3 * (size_t)ACT_LD);

    float acc[16];
#pragma unroll
    for (int i = 0; i < 16; ++i) acc[i] = 0.f;

#pragma unroll 2
    for (int k = tid; k < K4; k += 256) {
        float4 vw0 = w0[k], vw1 = w1[k], vw2 = w2[k], vw3 = w3[k];
        float4 va0 = a0[k], va1 = a1[k], va2 = a2[k], va3 = a3[k];
        acc[0]  += DOT4(vw0, va0); acc[1]  += DOT4(vw0, va1); acc[2]  += DOT4(vw0, va2); acc[3]  += DOT4(vw0, va3);
        acc[4]  += DOT4(vw1, va0); acc[5]  += DOT4(vw1, va1); acc[6]  += DOT4(vw1, va2); acc[7]  += DOT4(vw1, va3);
        acc[8]  += DOT4(vw2, va0); acc[9]  += DOT4(vw2, va1); acc[10] += DOT4(vw2, va2); acc[11] += DOT4(vw2, va3);
        acc[12] += DOT4(vw3, va0); acc[13] += DOT4(vw3, va1); acc[14] += DOT4(vw3, va2); acc[15] += DOT4(vw3, va3);
    }

#pragma unroll
    for (int i = 0; i < 16; ++i) acc[i] = wave_reduce_sum(acc[i]);

    __shared__ float lds[4][16];
    int wave = tid >> 6, lane = tid & 63;
    if (lane == 0) {
#pragma unroll
        for (int i = 0; i < 16; ++i) lds[wave][i] = acc[i];
    }
    __syncthreads();

    if (tid < 16) {
        float v  = lds[0][tid] + lds[1][tid] + lds[2][tid] + lds[3][tid];
        int   jj = tid >> 2, rr = tid & 3;
        int   j  = j0 + jj;
        v += bias[j];
        if (RELU) v = fmaxf(v, 0.f);
        out[(size_t)rr * OUT_LD + j] = v;
    }
}

// ---------------------------------------------------------------------------
// Kernel 5: class logits (21 rows -> ws) + regr (80 rows -> d_out[84..]).
// grid = 101 blocks. K = 2048.
// ---------------------------------------------------------------------------
__global__ __launch_bounds__(256) void head_kernel(const float* __restrict__ h2,
                                                   const float* __restrict__ d3_w,
                                                   const float* __restrict__ d4_w,
                                                   float* __restrict__ logits,
                                                   float* __restrict__ out) {
    int i = blockIdx.x;   // 0..100
    const float* wrow = (i < NCLS) ? (d3_w + (size_t)i * H2SZ)
                                   : (d4_w + (size_t)(i - NCLS) * H2SZ);
    int tid = threadIdx.x;
    const float4* w4 = (const float4*)wrow;
    const float4* a0 = (const float4*)(h2);
    const float4* a1 = (const float4*)(h2 + H2SZ);
    const float4* a2 = (const float4*)(h2 + 2 * H2SZ);
    const float4* a3 = (const float4*)(h2 + 3 * H2SZ);

    float acc0 = 0.f, acc1 = 0.f, acc2 = 0.f, acc3 = 0.f;
#pragma unroll 2
    for (int k = tid; k < 512; k += 256) {
        float4 w = w4[k];
        acc0 += DOT4(w, a0[k]);
        acc1 += DOT4(w, a1[k]);
        acc2 += DOT4(w, a2[k]);
        acc3 += DOT4(w, a3[k]);
    }
    acc0 = wave_reduce_sum(acc0);
    acc1 = wave_reduce_sum(acc1);
    acc2 = wave_reduce_sum(acc2);
    acc3 = wave_reduce_sum(acc3);

    __shared__ float lds[4][4];
    int wave = tid >> 6, lane = tid & 63;
    if (lane == 0) { lds[wave][0] = acc0; lds[wave][1] = acc1; lds[wave][2] = acc2; lds[wave][3] = acc3; }
    __syncthreads();

    if (tid < 4) {
        float v = lds[0][tid] + lds[1][tid] + lds[2][tid] + lds[3][tid];
        if (i < NCLS) logits[tid * NCLS + i] = v;
        else          out[NROI * NCLS + tid * NREG + (i - NCLS)] = v;
    }
}

// ---------------------------------------------------------------------------
// Kernel 6: softmax over 21 classes per roi. 1 block, wave = roi.
// ---------------------------------------------------------------------------
__global__ __launch_bounds__(256) void softmax_kernel(const float* __restrict__ logits,
                                                      float* __restrict__ out) {
    int tid = threadIdx.x;
    int r = tid >> 6, lane = tid & 63;
    float v = (lane < NCLS) ? logits[r * NCLS + lane] : -INFINITY;
    float m = v;
#pragma unroll
    for (int off = 32; off >= 1; off >>= 1)
        m = fmaxf(m, __shfl_xor(m, off, 64));
    float e = (lane < NCLS) ? expf(v - m) : 0.f;
    float s = wave_reduce_sum(e);
    if (lane < NCLS) out[r * NCLS + lane] = e / s;
}

// ---------------------------------------------------------------------------
extern "C" void kernel_launch(void* const* d_in, const int* in_sizes, int n_in,
                              void* d_out, int out_size, void* d_ws, size_t ws_size,
                              hipStream_t stream) {
    (void)in_sizes; (void)n_in; (void)out_size; (void)ws_size;
    const float* base_x = (const float*)d_in[0];
    const int*   rois   = (const int*)d_in[1];
    const float* conv_w = (const float*)d_in[2];
    const float* conv_b = (const float*)d_in[3];
    const float* d1_w   = (const float*)d_in[4];
    const float* d1_b   = (const float*)d_in[5];
    const float* d2_w   = (const float*)d_in[6];
    const float* d2_b   = (const float*)d_in[7];
    const float* d3_w   = (const float*)d_in[8];
    const float* d4_w   = (const float*)d_in[9];
    float* out = (float*)d_out;

    // workspace carve (all offsets 16B-aligned); total ~2.1 MB
    char*  ws     = (char*)d_ws;
    float* pooled = (float*)(ws);                 // 4*2048*49   = 1,605,632 B
    float* flat   = (float*)(ws + 1605632);       // 4*25088    =   401,408 B
    float* h1     = (float*)(ws + 2007040);       // 4*4096     =    65,536 B
    float* h2     = (float*)(ws + 2072576);       // 4*2048     =    32,768 B
    float* logits = (float*)(ws + 2105344);       // 4*21       =       336 B

    pool_kernel<<<NROI * (FEAT / 4), 256, 0, stream>>>(base_x, rois, pooled);
    conv_kernel<<<NROI * (RED / 4), 256, 0, stream>>>(pooled, conv_w, conv_b, flat);
    gemv_rows4<FLATSZ / 4, FLATSZ, H1SZ, true><<<H1SZ / 4, 256, 0, stream>>>(flat, d1_w, d1_b, h1);
    gemv_rows4<H1SZ / 4, H1SZ, H2SZ, true><<<H2SZ / 4, 256, 0, stream>>>(h1, d2_w, d2_b, h2);
    head_kernel<<<NCLS + NREG, 256, 0, stream>>>(h2, d3_w, d4_w, logits, out);
    softmax_kernel<<<1, 256, 0, stream>>>(logits, out);
}